// Round 7
// baseline (353.979 us; speedup 1.0000x reference)
//
#include <hip/hip_runtime.h>
#include <hip/hip_cooperative_groups.h>
#include <stdint.h>

namespace cg = cooperative_groups;

#define S_TOK 8192
#define D_DIM 768
#define B_SZ  4
#define K_TOP 512
#define NSLICE 32
#define SLICE (S_TOK / NSLICE)  // 256
#define NBLK 1024               // 4 blocks/CU x 256 CUs -> cooperative co-residency

// Single cooperative kernel: phase1 norms -> sync -> phase2 all-pairs rank partials
// -> sync -> phase3 rank-sum + compact map -> sync -> phase4 gather+mean.
// No LDS, no atomics; co-residency: 256 thr/block, >=4 waves/EU => VGPR<=128.
__global__ __launch_bounds__(256, 4) void fused_kernel(const float4* __restrict__ h4,
                                                       float4* __restrict__ out4,
                                                       uint32_t* __restrict__ imp_u,
                                                       uint32_t* __restrict__ partial,
                                                       int* __restrict__ map) {
    const int tid = threadIdx.x;
    const int blk = blockIdx.x;
    const int lane = tid & 63;
    const int w = tid >> 6;  // wave id 0..3
    const int D4 = D_DIM / 4;               // 192
    const size_t SB = (size_t)S_TOK * D4;   // batch stride in float4

    // ---------------- Phase 1: importance[s] = 0.25 * sum_b ||h[b,s,:]|| ----------
    // Wave per token, 2 tokens per wave; 12 independent float4 loads per token.
#pragma unroll 1
    for (int i = 0; i < 2; ++i) {
        const int s = blk * 8 + w * 2 + i;
        const float4* r = h4 + (size_t)s * D4 + lane;
        float4 v0 = r[0],          v1 = r[64],          v2 = r[128];
        float4 v3 = r[SB],         v4 = r[SB + 64],     v5 = r[SB + 128];
        float4 v6 = r[2 * SB],     v7 = r[2 * SB + 64], v8 = r[2 * SB + 128];
        float4 v9 = r[3 * SB],     vA = r[3 * SB + 64], vB = r[3 * SB + 128];

        float d0 = v0.x * v0.x + v0.y * v0.y + v0.z * v0.z + v0.w * v0.w;
        float d1 = v1.x * v1.x + v1.y * v1.y + v1.z * v1.z + v1.w * v1.w;
        float d2 = v2.x * v2.x + v2.y * v2.y + v2.z * v2.z + v2.w * v2.w;
        float d3 = v3.x * v3.x + v3.y * v3.y + v3.z * v3.z + v3.w * v3.w;
        float d4 = v4.x * v4.x + v4.y * v4.y + v4.z * v4.z + v4.w * v4.w;
        float d5 = v5.x * v5.x + v5.y * v5.y + v5.z * v5.z + v5.w * v5.w;
        float d6 = v6.x * v6.x + v6.y * v6.y + v6.z * v6.z + v6.w * v6.w;
        float d7 = v7.x * v7.x + v7.y * v7.y + v7.z * v7.z + v7.w * v7.w;
        float d8 = v8.x * v8.x + v8.y * v8.y + v8.z * v8.z + v8.w * v8.w;
        float d9 = v9.x * v9.x + v9.y * v9.y + v9.z * v9.z + v9.w * v9.w;
        float dA = vA.x * vA.x + vA.y * vA.y + vA.z * vA.z + vA.w * vA.w;
        float dB = vB.x * vB.x + vB.y * vB.y + vB.z * vB.z + vB.w * vB.w;

        // same per-row FP order as previous (passing) rounds
        float a0 = d0 + d1 + d2;
        float a1 = d3 + d4 + d5;
        float a2 = d6 + d7 + d8;
        float a3 = d9 + dA + dB;
#pragma unroll
        for (int off = 32; off >= 1; off >>= 1) {
            a0 += __shfl_xor(a0, off);
            a1 += __shfl_xor(a1, off);
            a2 += __shfl_xor(a2, off);
            a3 += __shfl_xor(a3, off);
        }
        if (lane == 0) {
            float acc = sqrtf(a0) + sqrtf(a1) + sqrtf(a2) + sqrtf(a3);
            imp_u[s] = __float_as_uint(acc * 0.25f);  // norms >= 0: bits order-compare
        }
    }
    cg::this_grid().sync();

    // ---------------- Phase 2: all-pairs partial rank ----------------
    // rank(s) = #{s' : key[s'] > key[s] || (key[s'] == key[s] && s' < s)}.
    // Block (grp,c): tokens [grp*256,+256) vs keys [c*256,+256); slice reads are
    // wave-uniform -> scalar loads through K$.
    {
        const int grp = blk >> 5;
        const int c = blk & 31;
        const int s = grp * 256 + tid;
        const uint32_t ks = imp_u[s];
        const uint4* slice4 = (const uint4*)(imp_u + c * SLICE);
        uint32_t cnt = 0;
#pragma unroll 8
        for (int j4 = 0; j4 < SLICE / 4; ++j4) {
            uint4 kv = slice4[j4];
            const int jb = c * SLICE + j4 * 4;
            cnt += (kv.x > ks || (kv.x == ks && (jb + 0) < s)) ? 1u : 0u;
            cnt += (kv.y > ks || (kv.y == ks && (jb + 1) < s)) ? 1u : 0u;
            cnt += (kv.z > ks || (kv.z == ks && (jb + 2) < s)) ? 1u : 0u;
            cnt += (kv.w > ks || (kv.w == ks && (jb + 3) < s)) ? 1u : 0u;
        }
        partial[c * S_TOK + s] = cnt;
    }
    cg::this_grid().sync();

    // ---------------- Phase 3: rank sum + compact map[rank] = token (blocks 0..31) --
    if (blk < 32) {
        const int s = blk * 256 + tid;
        uint32_t r = 0;
#pragma unroll
        for (int c = 0; c < NSLICE; ++c) r += partial[c * S_TOK + s];
        if (r < K_TOP) map[r] = s;  // ranks are a bijection over tokens
    }
    cg::this_grid().sync();

    // ---------------- Phase 4: out[r,:] = 0.25 * sum_b h[b, map[r], :] (blocks 0..511)
    if (blk < K_TOP && tid < D4) {
        const int idx = map[blk];
        const float4* base = h4 + (size_t)idx * D4;
        float4 a = base[tid];
        float4 b = base[tid + SB];
        float4 c = base[tid + 2 * SB];
        float4 e = base[tid + 3 * SB];
        float4 r;
        r.x = 0.25f * (a.x + b.x + c.x + e.x);
        r.y = 0.25f * (a.y + b.y + c.y + e.y);
        r.z = 0.25f * (a.z + b.z + c.z + e.z);
        r.w = 0.25f * (a.w + b.w + c.w + e.w);
        out4[(size_t)blk * D4 + tid] = r;
    }
}

extern "C" void kernel_launch(void* const* d_in, const int* in_sizes, int n_in,
                              void* d_out, int out_size, void* d_ws, size_t ws_size,
                              hipStream_t stream) {
    const float4* h4 = (const float4*)d_in[0];
    // d_in[1] (memory) is dead: k == MEMORY_SIZE, every row is overwritten.
    float4* out4 = (float4*)d_out;
    uint32_t* imp_u = (uint32_t*)d_ws;
    uint32_t* partial = (uint32_t*)((char*)d_ws + S_TOK * sizeof(uint32_t));
    int* map = (int*)((char*)d_ws + S_TOK * sizeof(uint32_t) + NSLICE * S_TOK * sizeof(uint32_t));

    void* args[] = {(void*)&h4, (void*)&out4, (void*)&imp_u, (void*)&partial, (void*)&map};
    hipLaunchCooperativeKernel((const void*)fused_kernel, dim3(NBLK), dim3(256), args, 0,
                               stream);
}

// Round 8
// 43.518 us; speedup vs baseline: 8.1340x; 8.1340x over previous
//
#include <hip/hip_runtime.h>
#include <stdint.h>

#define S_TOK 8192
#define D_DIM 768
#define B_SZ  4
#define K_TOP 512
#define NSLICE 32
#define SLICE (S_TOK / NSLICE)  // 256
#define NT_TOK 5632             // tokens via nontemporal-load path (A)
                                // remaining 2560 via global_load_lds path (B)

typedef float f4v __attribute__((ext_vector_type(4)));

__device__ __forceinline__ float sq4(f4v v) {
    // same FP order as all passing rounds: ((x^2+y^2)+z^2)+w^2
    return v[0] * v[0] + v[1] * v[1] + v[2] * v[2] + v[3] * v[3];
}

// ---------------- Kernel 1A: importance via NONTEMPORAL loads (tokens [0, NT_TOK)) --
// One wave per token; 12 independent nt float4 loads (L1 no-allocate hint).
__global__ __launch_bounds__(256) void importance_nt_kernel(const f4v* __restrict__ h4,
                                                            uint32_t* __restrict__ imp_u) {
    const int D4 = D_DIM / 4;               // 192
    const size_t SB = (size_t)S_TOK * D4;   // batch stride in float4
    const int wave = (blockIdx.x * blockDim.x + threadIdx.x) >> 6;  // token < NT_TOK
    const int lane = threadIdx.x & 63;
    const f4v* r = h4 + (size_t)wave * D4 + lane;

    f4v v0 = __builtin_nontemporal_load(r);
    f4v v1 = __builtin_nontemporal_load(r + 64);
    f4v v2 = __builtin_nontemporal_load(r + 128);
    f4v v3 = __builtin_nontemporal_load(r + SB);
    f4v v4 = __builtin_nontemporal_load(r + SB + 64);
    f4v v5 = __builtin_nontemporal_load(r + SB + 128);
    f4v v6 = __builtin_nontemporal_load(r + 2 * SB);
    f4v v7 = __builtin_nontemporal_load(r + 2 * SB + 64);
    f4v v8 = __builtin_nontemporal_load(r + 2 * SB + 128);
    f4v v9 = __builtin_nontemporal_load(r + 3 * SB);
    f4v vA = __builtin_nontemporal_load(r + 3 * SB + 64);
    f4v vB = __builtin_nontemporal_load(r + 3 * SB + 128);

    float a0 = sq4(v0) + sq4(v1) + sq4(v2);
    float a1 = sq4(v3) + sq4(v4) + sq4(v5);
    float a2 = sq4(v6) + sq4(v7) + sq4(v8);
    float a3 = sq4(v9) + sq4(vA) + sq4(vB);
#pragma unroll
    for (int off = 32; off >= 1; off >>= 1) {
        a0 += __shfl_xor(a0, off);
        a1 += __shfl_xor(a1, off);
        a2 += __shfl_xor(a2, off);
        a3 += __shfl_xor(a3, off);
    }
    if (lane == 0) {
        float acc = sqrtf(a0) + sqrtf(a1) + sqrtf(a2) + sqrtf(a3);
        imp_u[wave] = __float_as_uint(acc * 0.25f);  // norms >= 0: bits order-compare
    }
}

// ---------------- Kernel 1B: importance via global_load_lds DMA (tokens [NT_TOK, S)) --
// One wave per token; 12 x 1KB LDS-DMA chunks (wave-uniform LDS base + lane*16),
// vmcnt drain, then ds_read_b128 back and identical math.
#define AS1C(p) ((const __attribute__((address_space(1))) void*)(p))
#define AS3(p)  ((__attribute__((address_space(3))) void*)(p))

__global__ __launch_bounds__(256) void importance_glds_kernel(const float* __restrict__ h,
                                                              uint32_t* __restrict__ imp_u) {
    __shared__ char smem[4 * 12 * 1024];  // 4 waves x 12 chunks x 1 KB = 48 KB
    const int w = threadIdx.x >> 6;
    const int lane = threadIdx.x & 63;
    const int s = NT_TOK + blockIdx.x * 4 + w;
    char* base = smem + w * 12288;

#pragma unroll
    for (int b = 0; b < B_SZ; ++b) {
#pragma unroll
        for (int p = 0; p < 3; ++p) {
            const float* g = h + ((size_t)b * S_TOK + (size_t)s) * D_DIM + p * 256 + lane * 4;
            __builtin_amdgcn_global_load_lds(AS1C(g), AS3(base + (b * 3 + p) * 1024), 16, 0, 0);
        }
    }
    asm volatile("s_waitcnt vmcnt(0)" ::: "memory");

    float a0, a1, a2, a3;
    {
        f4v u0 = *(const f4v*)(base + 0 * 1024 + lane * 16);
        f4v u1 = *(const f4v*)(base + 1 * 1024 + lane * 16);
        f4v u2 = *(const f4v*)(base + 2 * 1024 + lane * 16);
        a0 = sq4(u0) + sq4(u1) + sq4(u2);
        f4v u3 = *(const f4v*)(base + 3 * 1024 + lane * 16);
        f4v u4 = *(const f4v*)(base + 4 * 1024 + lane * 16);
        f4v u5 = *(const f4v*)(base + 5 * 1024 + lane * 16);
        a1 = sq4(u3) + sq4(u4) + sq4(u5);
        f4v u6 = *(const f4v*)(base + 6 * 1024 + lane * 16);
        f4v u7 = *(const f4v*)(base + 7 * 1024 + lane * 16);
        f4v u8 = *(const f4v*)(base + 8 * 1024 + lane * 16);
        a2 = sq4(u6) + sq4(u7) + sq4(u8);
        f4v u9 = *(const f4v*)(base + 9 * 1024 + lane * 16);
        f4v uA = *(const f4v*)(base + 10 * 1024 + lane * 16);
        f4v uB = *(const f4v*)(base + 11 * 1024 + lane * 16);
        a3 = sq4(u9) + sq4(uA) + sq4(uB);
    }
#pragma unroll
    for (int off = 32; off >= 1; off >>= 1) {
        a0 += __shfl_xor(a0, off);
        a1 += __shfl_xor(a1, off);
        a2 += __shfl_xor(a2, off);
        a3 += __shfl_xor(a3, off);
    }
    if (lane == 0) {
        float acc = sqrtf(a0) + sqrtf(a1) + sqrtf(a2) + sqrtf(a3);
        imp_u[s] = __float_as_uint(acc * 0.25f);
    }
}

// ---------------- Kernel 2: all-pairs partial rank ----------------
__global__ __launch_bounds__(256) void rank_kernel(const uint32_t* __restrict__ imp_u,
                                                   uint32_t* __restrict__ partial) {
    const int grp = blockIdx.x >> 5;   // 0..31
    const int c   = blockIdx.x & 31;   // 0..31
    const int s   = grp * 256 + threadIdx.x;
    const uint32_t ks = imp_u[s];
    const uint4* slice4 = (const uint4*)(imp_u + c * SLICE);
    uint32_t cnt = 0;
#pragma unroll 8
    for (int j4 = 0; j4 < SLICE / 4; ++j4) {
        uint4 kv = slice4[j4];                 // uniform -> s_load_dwordx4
        const int jb = c * SLICE + j4 * 4;
        cnt += (kv.x > ks || (kv.x == ks && (jb + 0) < s)) ? 1u : 0u;
        cnt += (kv.y > ks || (kv.y == ks && (jb + 1) < s)) ? 1u : 0u;
        cnt += (kv.z > ks || (kv.z == ks && (jb + 2) < s)) ? 1u : 0u;
        cnt += (kv.w > ks || (kv.w == ks && (jb + 3) < s)) ? 1u : 0u;
    }
    partial[c * S_TOK + s] = cnt;              // coalesced
}

// ---------------- Kernel 3: sum partials -> rank; compact map[rank] = token ----------
__global__ __launch_bounds__(256) void summap_kernel(const uint32_t* __restrict__ partial,
                                                     int* __restrict__ map) {
    const int s = blockIdx.x * 256 + threadIdx.x;
    uint32_t r = 0;
#pragma unroll
    for (int c = 0; c < NSLICE; ++c) r += partial[c * S_TOK + s];
    if (r < K_TOP) map[r] = s;  // ranks are a bijection; 512 scattered 4B stores
}

// ---------------- Kernel 4: out[r,:] = 0.25 * sum_b h[b, map[r], :] ----------------
__global__ __launch_bounds__(192) void gather_kernel(const float4* __restrict__ h4,
                                                     const int* __restrict__ map,
                                                     float4* __restrict__ out4) {
    const int D4 = D_DIM / 4;  // 192
    const size_t SD4 = (size_t)S_TOK * D4;
    const int idx = map[blockIdx.x];
    const float4* base = h4 + (size_t)idx * D4;
    const int d = threadIdx.x;
    float4 a = base[d];
    float4 b = base[d + SD4];
    float4 c = base[d + 2 * SD4];
    float4 e = base[d + 3 * SD4];
    float4 r;
    r.x = 0.25f * (a.x + b.x + c.x + e.x);
    r.y = 0.25f * (a.y + b.y + c.y + e.y);
    r.z = 0.25f * (a.z + b.z + c.z + e.z);
    r.w = 0.25f * (a.w + b.w + c.w + e.w);
    out4[(size_t)blockIdx.x * D4 + d] = r;
}

extern "C" void kernel_launch(void* const* d_in, const int* in_sizes, int n_in,
                              void* d_out, int out_size, void* d_ws, size_t ws_size,
                              hipStream_t stream) {
    const float* h = (const float*)d_in[0];
    // d_in[1] (memory) is dead: k == MEMORY_SIZE, every row is overwritten.
    float* out = (float*)d_out;
    uint32_t* imp_u = (uint32_t*)d_ws;
    uint32_t* partial = (uint32_t*)((char*)d_ws + S_TOK * sizeof(uint32_t));
    int* map = (int*)((char*)d_ws + S_TOK * sizeof(uint32_t) + NSLICE * S_TOK * sizeof(uint32_t));

    importance_nt_kernel<<<NT_TOK / 4, 256, 0, stream>>>((const f4v*)h, imp_u);
    importance_glds_kernel<<<(S_TOK - NT_TOK) / 4, 256, 0, stream>>>(h, imp_u);
    rank_kernel<<<NSLICE * (S_TOK / 256), 256, 0, stream>>>(imp_u, partial);
    summap_kernel<<<S_TOK / 256, 256, 0, stream>>>(partial, map);
    gather_kernel<<<K_TOP, 192, 0, stream>>>((const float4*)h, map, (float4*)out);
}

// Round 9
// 42.025 us; speedup vs baseline: 8.4231x; 1.0355x over previous
//
#include <hip/hip_runtime.h>
#include <stdint.h>

#define S_TOK 8192
#define D_DIM 768
#define B_SZ  4
#define K_TOP 512

// ---------------- Kernel A: importance[s] = 0.25 * sum_b ||h[b,s,:]|| ----------------
// One wave per token; 12 independent float4 loads; butterfly tails. (R5 structure —
// verified absmax 0.0; k1 variants are perf-equivalent, this is the simplest.)
__global__ __launch_bounds__(256) void importance_kernel(const float4* __restrict__ h4,
                                                         uint32_t* __restrict__ imp_u) {
    const int D4 = D_DIM / 4;               // 192
    const size_t SB = (size_t)S_TOK * D4;   // batch stride in float4
    const int wave = (blockIdx.x * blockDim.x + threadIdx.x) >> 6;  // token, < 8192
    const int lane = threadIdx.x & 63;
    const float4* r = h4 + (size_t)wave * D4 + lane;

    float4 v0 = r[0 * SB + 0],  v1 = r[0 * SB + 64],  v2 = r[0 * SB + 128];
    float4 v3 = r[1 * SB + 0],  v4 = r[1 * SB + 64],  v5 = r[1 * SB + 128];
    float4 v6 = r[2 * SB + 0],  v7 = r[2 * SB + 64],  v8 = r[2 * SB + 128];
    float4 v9 = r[3 * SB + 0],  vA = r[3 * SB + 64],  vB = r[3 * SB + 128];

    float d0 = v0.x * v0.x + v0.y * v0.y + v0.z * v0.z + v0.w * v0.w;
    float d1 = v1.x * v1.x + v1.y * v1.y + v1.z * v1.z + v1.w * v1.w;
    float d2 = v2.x * v2.x + v2.y * v2.y + v2.z * v2.z + v2.w * v2.w;
    float d3 = v3.x * v3.x + v3.y * v3.y + v3.z * v3.z + v3.w * v3.w;
    float d4 = v4.x * v4.x + v4.y * v4.y + v4.z * v4.z + v4.w * v4.w;
    float d5 = v5.x * v5.x + v5.y * v5.y + v5.z * v5.z + v5.w * v5.w;
    float d6 = v6.x * v6.x + v6.y * v6.y + v6.z * v6.z + v6.w * v6.w;
    float d7 = v7.x * v7.x + v7.y * v7.y + v7.z * v7.z + v7.w * v7.w;
    float d8 = v8.x * v8.x + v8.y * v8.y + v8.z * v8.z + v8.w * v8.w;
    float d9 = v9.x * v9.x + v9.y * v9.y + v9.z * v9.z + v9.w * v9.w;
    float dA = vA.x * vA.x + vA.y * vA.y + vA.z * vA.z + vA.w * vA.w;
    float dB = vB.x * vB.x + vB.y * vB.y + vB.z * vB.z + vB.w * vB.w;

    float a0 = d0 + d1 + d2;
    float a1 = d3 + d4 + d5;
    float a2 = d6 + d7 + d8;
    float a3 = d9 + dA + dB;
#pragma unroll
    for (int off = 32; off >= 1; off >>= 1) {
        a0 += __shfl_xor(a0, off);
        a1 += __shfl_xor(a1, off);
        a2 += __shfl_xor(a2, off);
        a3 += __shfl_xor(a3, off);
    }
    if (lane == 0) {
        float acc = sqrtf(a0) + sqrtf(a1) + sqrtf(a2) + sqrtf(a3);
        // norms are >= 0, so float bits compare as uint32 — store bits directly
        imp_u[wave] = __float_as_uint(acc * 0.25f);
    }
}

// ---------------- Kernel B: rank + pick + gather, fused ----------------
// 512 blocks x 256 threads. Block b owns tokens [b*16, b*16+16). Thread (sl,tt)
// (sl=tid>>4, tt=tid&15) counts token tt's rank contribution over key slice
// [sl*512, sl*512+512) (imp is 32 KB, L2-resident). LDS 16x16 reduce -> exact rank
// (bijection). Winners (rank < 512, avg 1/block) are gathered by the whole block:
// out[rank,:] = 0.25 * sum_b h[b, token, :].
__global__ __launch_bounds__(256) void rank_gather_kernel(const uint32_t* __restrict__ imp_u,
                                                          const float4* __restrict__ h4,
                                                          float4* __restrict__ out4) {
    const int tid = threadIdx.x;
    const int tt = tid & 15;   // token within block
    const int sl = tid >> 4;   // key slice 0..15
    const int s = blockIdx.x * 16 + tt;  // global token
    __shared__ uint32_t s_part[16][17];  // [sl][tt], +1 pad: conflict-free columns
    __shared__ int s_wtok[16];
    __shared__ int s_wrank[16];
    __shared__ int s_nw;

    // rank contribution: #{j in slice : key[j] > ks || (key[j] == ks && j < s)}
    const uint32_t ks = imp_u[s];
    const uint4* sp = (const uint4*)(imp_u + sl * 512);
    uint32_t cnt = 0;
#pragma unroll 8
    for (int j4 = 0; j4 < 128; ++j4) {
        uint4 kv = sp[j4];
        const int jb = sl * 512 + j4 * 4;
        cnt += (kv.x > ks || (kv.x == ks && (jb + 0) < s)) ? 1u : 0u;
        cnt += (kv.y > ks || (kv.y == ks && (jb + 1) < s)) ? 1u : 0u;
        cnt += (kv.z > ks || (kv.z == ks && (jb + 2) < s)) ? 1u : 0u;
        cnt += (kv.w > ks || (kv.w == ks && (jb + 3) < s)) ? 1u : 0u;
    }
    s_part[sl][tt] = cnt;
    if (tid == 0) s_nw = 0;
    __syncthreads();

    if (tid < 16) {
        uint32_t r = 0;
#pragma unroll
        for (int k = 0; k < 16; ++k) r += s_part[k][tid];
        if (r < K_TOP) {  // winner: record (token, rank); order within block irrelevant
            int w = atomicAdd(&s_nw, 1);
            s_wtok[w] = blockIdx.x * 16 + tid;
            s_wrank[w] = (int)r;
        }
    }
    __syncthreads();

    const int nw = s_nw;
    const int D4 = D_DIM / 4;  // 192
    const size_t SB = (size_t)S_TOK * D4;
    for (int w = 0; w < nw; ++w) {
        const int idx = s_wtok[w];
        const int rk = s_wrank[w];
        if (tid < D4) {
            const float4* base = h4 + (size_t)idx * D4;
            float4 a = base[tid];
            float4 b = base[tid + SB];
            float4 c = base[tid + 2 * SB];
            float4 e = base[tid + 3 * SB];
            float4 r4;
            r4.x = 0.25f * (a.x + b.x + c.x + e.x);
            r4.y = 0.25f * (a.y + b.y + c.y + e.y);
            r4.z = 0.25f * (a.z + b.z + c.z + e.z);
            r4.w = 0.25f * (a.w + b.w + c.w + e.w);
            out4[(size_t)rk * D4 + tid] = r4;
        }
    }
}

extern "C" void kernel_launch(void* const* d_in, const int* in_sizes, int n_in,
                              void* d_out, int out_size, void* d_ws, size_t ws_size,
                              hipStream_t stream) {
    const float* h = (const float*)d_in[0];
    // d_in[1] (memory) is dead: k == MEMORY_SIZE, every row is overwritten.
    float* out = (float*)d_out;
    uint32_t* imp_u = (uint32_t*)d_ws;

    importance_kernel<<<S_TOK / 4, 256, 0, stream>>>((const float4*)h, imp_u);
    rank_gather_kernel<<<K_TOP, 256, 0, stream>>>(imp_u, (const float4*)h, (float4*)out);
}